// Round 12
// baseline (146.940 us; speedup 1.0000x reference)
//
#include <hip/hip_runtime.h>
#include <cmath>

#define HH 512
#define WW 512
#define TW 32
#define TH 64          /* output rows per tile: halo redundancy 74/64 = 1.16x */
#define INH 74         /* TH + 10 halo rows */
#define TWP 33         /* padded tile width in pixels */
#define NTHREADS 640   /* 10 waves: 592 phase-B tasks fit in ONE round (was 2) */
#define NCW 512        /* phase-C active threads: 512 x 4 outputs = 32x64 tile */
#define NXT 16         /* x tiles */
#define NYT 8          /* y tiles */
#define NPL 48
#define NBLK (NXT * NYT * NPL)   /* 6144 */
#define C1F 0.0001f
#define C2F 0.0009f

typedef float v2f __attribute__((ext_vector_type(2)));

struct GaussW { float w[11]; };

__device__ __forceinline__ void load16a4(const float* __restrict__ p, float v[16]) {
    *(float4*)&v[0]  = *(const float4*)(p);
    *(float4*)&v[4]  = *(const float4*)(p + 4);
    *(float4*)&v[8]  = *(const float4*)(p + 8);
    *(float4*)&v[12] = *(const float4*)(p + 12);
}
__device__ __forceinline__ void load16a2(const float* __restrict__ p, float v[16]) {
    *(float2*)&v[0]  = *(const float2*)(p);
    *(float4*)&v[2]  = *(const float4*)(p + 2);
    *(float4*)&v[6]  = *(const float4*)(p + 6);
    *(float4*)&v[10] = *(const float4*)(p + 10);
    *(float2*)&v[14] = *(const float2*)(p + 14);
}

// R12 = R11 + (a) NTHREADS 512->640: 592 phase-B tasks in ONE round (R11:
// round 2 ran on 80/512 threads while 432 idled at the barrier = ~42% of
// phase-B wall wasted); phase C keeps the proven 512-thread mapping.
// (b) j-outer conv with hoisted v^2: per task 14 pk_mul + 88 pk_fma = 102
// ops vs 132 (inner was 3 ops/tap: wv=wk*v; s1+=wv; s2+=wv*v). j-outer
// order keeps liveness minimal (v,v2 + 16 acc), same as phase C.
// Kept: packed f32 (R11, -10%), XCD-bijective remap (FETCH 141->49MB),
// phi(4g+o)=(g^2o)+8o LDS swizzle (conflicts 0), vectorized boundaries,
// TH=64 tile, unrolled finalize.
// CONFIRMED rule (R1, R5): never pass a min-waves arg to __launch_bounds__ -
// forces VGPR=40 + scratch spill. VGPR tripwire: <=64 for 8 waves/SIMD.
__global__ __launch_bounds__(NTHREADS) void ssim_tile_kernel(
    const float* __restrict__ pred, const float* __restrict__ targ,
    float* __restrict__ partial, GaussW gw)
{
    __shared__ __align__(16) float hp[INH][TWP][4];
    __shared__ float wred[10];

    const int tid = threadIdx.x;

    // ---- XCD-bijective work remap: lid%8 = hw XCD (round-robin) ----
    const int lid = (blockIdx.z * gridDim.y + blockIdx.y) * gridDim.x + blockIdx.x;
    const int wi  = (lid & 7) * (NBLK / 8) + (lid >> 3);
    const int bx  = wi & (NXT - 1);
    const int by  = (wi >> 4) & (NYT - 1);
    const int bz  = wi >> 7;

    const int gx0 = bx * TW;
    const int gy0 = by * TH - 5;
    const size_t plane = (size_t)bz * (size_t)(HH * WW);

    const bool lblk = (bx == 0);
    const bool rblk = (bx == NXT - 1);

    // ---- Phase B: horizontal Gaussian on (a,b,a^2,b^2) from global ----
    // 592 tasks: 74 rows x 8 col-groups, 4 output cols each; ONE round.
    if (tid < INH * 8) {
        const int i = tid;
        int r = i >> 3;
        int g = i & 7;
        int c0 = g << 2;
        int gr = gy0 + r;

        if ((unsigned)gr >= (unsigned)HH) {
            float4 z = make_float4(0.f, 0.f, 0.f, 0.f);
            #pragma unroll
            for (int o = 0; o < 4; o++) {
                int phys = (g ^ (o << 1)) + (o << 3);   // phi(c0+o)
                *(float4*)&hp[r][phys][0] = z;
            }
        } else {
            const float* prow = pred + plane + (size_t)gr * WW;
            const float* trow = targ + plane + (size_t)gr * WW;

            v2f ab[14];
            if (lblk && g < 2) {
                // window = cols 0..15; valid iff col >= 0
                float P[16], T[16];
                load16a4(prow, P);
                load16a4(trow, T);
                if (g == 0) {          // col = j-5, valid j>=5
                    #pragma unroll
                    for (int j = 0; j < 14; j++) {
                        float pv = (j >= 5) ? P[j - 5] : 0.f;
                        float tv = (j >= 5) ? T[j - 5] : 0.f;
                        ab[j] = (v2f){pv + tv, pv - tv};
                    }
                } else {               // g==1: col = j-1, valid j>=1
                    #pragma unroll
                    for (int j = 0; j < 14; j++) {
                        float pv = (j >= 1) ? P[j - 1] : 0.f;
                        float tv = (j >= 1) ? T[j - 1] : 0.f;
                        ab[j] = (v2f){pv + tv, pv - tv};
                    }
                }
            } else if (rblk && g > 5) {
                // window = cols 496..511; valid iff col <= 511
                float P[16], T[16];
                load16a4(prow + (WW - 16), P);
                load16a4(trow + (WW - 16), T);
                if (g == 6) {          // col = 499+j, idx j+3, valid j<=12
                    #pragma unroll
                    for (int j = 0; j < 14; j++) {
                        float pv = (j <= 12) ? P[j + 3] : 0.f;
                        float tv = (j <= 12) ? T[j + 3] : 0.f;
                        ab[j] = (v2f){pv + tv, pv - tv};
                    }
                } else {               // g==7: col = 503+j, idx j+7, valid j<=8
                    #pragma unroll
                    for (int j = 0; j < 14; j++) {
                        float pv = (j <= 8) ? P[j + 7] : 0.f;
                        float tv = (j <= 8) ? T[j + 7] : 0.f;
                        ab[j] = (v2f){pv + tv, pv - tv};
                    }
                }
            } else {
                // interior: window = cols gx0+c0-6 .. +9 (base = 2 mod 4 dwords)
                float P[16], T[16];
                load16a2(prow + gx0 + c0 - 6, P);
                load16a2(trow + gx0 + c0 - 6, T);
                #pragma unroll
                for (int j = 0; j < 14; j++) {
                    float pv = P[j + 1], tv = T[j + 1];
                    ab[j] = (v2f){pv + tv, pv - tv};
                }
            }

            // j-outer conv: v2 hoisted once per input; 2 pk_fma per (j,o).
            v2f s1[4], s2[4];
            #pragma unroll
            for (int o = 0; o < 4; o++) { s1[o] = (v2f)(0.f); s2[o] = (v2f)(0.f); }
            #pragma unroll
            for (int j = 0; j < 14; j++) {
                v2f v  = ab[j];
                v2f v2 = v * v;                 // v_pk_mul_f32
                #pragma unroll
                for (int o = 0; o < 4; o++) {
                    int k = j - o;
                    if (k >= 0 && k < 11) {
                        float wk = gw.w[k];
                        s1[o] += wk * v;        // v_pk_fma_f32
                        s2[o] += wk * v2;       // v_pk_fma_f32
                    }
                }
            }
            #pragma unroll
            for (int o = 0; o < 4; o++) {
                int phys = (g ^ (o << 1)) + (o << 3);   // phi(c0+o)
                *(float4*)&hp[r][phys][0] =
                    make_float4(s1[o].x, s1[o].y, s2[o].x, s2[o].y);
            }
        }
    }
    __syncthreads();

    // ---- Phase C: vertical Gaussian, 4 rows x 1 col per thread + SSIM ----
    // 512 active threads x 4 outputs = 2048 = 32x64 tile. One b128 read per
    // pixel; packed accumulation of (A,B) and (EA,EB).
    float local = 0.f;
    if (tid < NCW) {
        const int c0 = tid & 31;            // logical col 0..31
        const int r0 = (tid >> 5) << 2;     // 0..60
        const int pc = ((c0 >> 2) ^ ((c0 & 3) << 1)) + ((c0 & 3) << 3);  // phi(c0)
        const float* hbase = &hp[r0][pc][0];

        v2f accm[4], acce[4];
        #pragma unroll
        for (int rr = 0; rr < 4; rr++) { accm[rr] = (v2f)(0.f); acce[rr] = (v2f)(0.f); }

        #pragma unroll
        for (int jj = 0; jj < 14; jj++) {
            float4 v = *(const float4*)(hbase + (size_t)jj * (TWP * 4));
            v2f vm = (v2f){v.x, v.y};
            v2f ve = (v2f){v.z, v.w};
            #pragma unroll
            for (int rr = 0; rr < 4; rr++) {
                int k = jj - rr;
                if (k >= 0 && k < 11) {
                    float wk = gw.w[k];
                    accm[rr] += wk * vm;   // v_pk_fma_f32
                    acce[rr] += wk * ve;   // v_pk_fma_f32
                }
            }
        }

        #pragma unroll
        for (int rr = 0; rr < 4; rr++) {
            float A  = accm[rr].x, Bv = accm[rr].y;
            float EA = acce[rr].x, EB = acce[rr].y;
            float A2 = A * A, B2 = Bv * Bv;
            float S  = 0.5f  * (A2 + B2);      // mu1^2 + mu2^2
            float P  = 0.25f * (A2 - B2);      // mu1 * mu2
            float Ep = 0.5f  * (EA + EB);      // e11 + e22
            float Ec = 0.25f * (EA - EB);      // e12
            float num = (2.f * P + C1F) * (2.f * (Ec - P) + C2F);
            float den = (S + C1F) * ((Ep - S) + C2F);
            local += num * __builtin_amdgcn_rcpf(den);
        }
    }

    // ---- block reduction (10 waves; inactive threads carry local=0) ----
    #pragma unroll
    for (int off = 32; off > 0; off >>= 1)
        local += __shfl_down(local, off, 64);
    int lane = tid & 63, wid = tid >> 6;
    if (lane == 0) wred[wid] = local;
    __syncthreads();
    if (tid == 0) {
        float s = 0.f;
        #pragma unroll
        for (int w2 = 0; w2 < 10; w2++) s += wred[w2];
        partial[lid] = s;
    }
}

// Compile-time N=6144: 6 independent unrolled float4 loads per thread.
__global__ __launch_bounds__(256) void ssim_finalize_kernel(
    const float* __restrict__ partial, float inv_count,
    float* __restrict__ out)
{
    __shared__ float sm[4];
    float s = 0.f;
    #pragma unroll
    for (int i = 0; i < NBLK / 4 / 256; i++) {
        float4 v = *(const float4*)&partial[(threadIdx.x + i * 256) * 4];
        s += (v.x + v.y) + (v.z + v.w);
    }
    #pragma unroll
    for (int off = 32; off > 0; off >>= 1)
        s += __shfl_down(s, off, 64);
    int lane = threadIdx.x & 63, wid = threadIdx.x >> 6;
    if (lane == 0) sm[wid] = s;
    __syncthreads();
    if (threadIdx.x == 0)
        out[0] = 1.0f - (sm[0] + sm[1] + sm[2] + sm[3]) * inv_count;
}

extern "C" void kernel_launch(void* const* d_in, const int* in_sizes, int n_in,
                              void* d_out, int out_size, void* d_ws, size_t ws_size,
                              hipStream_t stream)
{
    const float* pred = (const float*)d_in[0];
    const float* targ = (const float*)d_in[1];
    float* out = (float*)d_out;
    float* partial = (float*)d_ws;

    const int total = in_sizes[0];                 // 16*3*512*512 = 12582912

    GaussW gw;
    double g[11], s = 0.0;
    for (int i = 0; i < 11; i++) {
        double d = (double)(i - 5);
        g[i] = exp(-d * d / 4.5);
        s += g[i];
    }
    for (int i = 0; i < 11; i++) gw.w[i] = (float)(g[i] / s);

    dim3 grid(NXT, NYT, NPL);                      // 16 x 8 x 48 = 6144 blocks
    ssim_tile_kernel<<<grid, NTHREADS, 0, stream>>>(pred, targ, partial, gw);

    const float inv_count = 1.0f / (float)total;
    ssim_finalize_kernel<<<1, 256, 0, stream>>>(partial, inv_count, out);
}

// Round 13
// 140.020 us; speedup vs baseline: 1.0494x; 1.0494x over previous
//
#include <hip/hip_runtime.h>
#include <cmath>

#define HH 512
#define WW 512
#define TW 32
#define TH 64          /* output rows per tile: halo redundancy 74/64 = 1.16x */
#define INH 74         /* TH + 10 halo rows */
#define TWP 33         /* padded tile width in pixels */
#define NTHREADS 512   /* 8 waves; LDS 39.4KB -> 4 blocks/CU = 32 waves/CU cap */
#define NXT 16         /* x tiles */
#define NYT 8          /* y tiles */
#define NPL 48
#define NBLK (NXT * NYT * NPL)   /* 6144 */
#define C1F 0.0001f
#define C2F 0.0009f

typedef float v2f __attribute__((ext_vector_type(2)));

struct GaussW { float w[11]; };

__device__ __forceinline__ void load16a4(const float* __restrict__ p, float v[16]) {
    *(float4*)&v[0]  = *(const float4*)(p);
    *(float4*)&v[4]  = *(const float4*)(p + 4);
    *(float4*)&v[8]  = *(const float4*)(p + 8);
    *(float4*)&v[12] = *(const float4*)(p + 12);
}
__device__ __forceinline__ void load16a2(const float* __restrict__ p, float v[16]) {
    *(float2*)&v[0]  = *(const float2*)(p);
    *(float4*)&v[2]  = *(const float4*)(p + 2);
    *(float4*)&v[6]  = *(const float4*)(p + 6);
    *(float4*)&v[10] = *(const float4*)(p + 10);
    *(float2*)&v[14] = *(const float2*)(p + 14);
}

// R13 = R11 structure (512 thr / 8 waves — best measured: 60.0us tile,
// occupancy 66%) + R12's j-outer conv ONLY.
// R12 post-mortem: 640-thr blocks REGRESSED (occupancy 66->44%: 3x10-wave
// blocks at the 32-wave cap = coarser wave mix, 2/10 waves idle in phase C,
// bigger convoys). One-round phase B didn't pay. Reverted.
// j-outer conv with hoisted v^2: 102 packed ops/task vs 132 (inner-order
// was wv=wk*v; s1+=wv; s2+=wv*v = 3 ops/tap; j-outer: v2=v*v once, then
// 2 pk_fma per valid (j,o)).
// Kept: packed f32 (R11), XCD-bijective remap (FETCH 141->49MB),
// phi(4g+o)=(g^2o)+8o LDS swizzle (conflicts 0), vectorized boundaries,
// TH=64 tile, unrolled finalize.
// CONFIRMED rule (R1, R5): never pass a min-waves arg to __launch_bounds__ -
// forces VGPR=40 + scratch spill. VGPR tripwire: <=64 for 8 waves/SIMD.
__global__ __launch_bounds__(NTHREADS) void ssim_tile_kernel(
    const float* __restrict__ pred, const float* __restrict__ targ,
    float* __restrict__ partial, GaussW gw)
{
    __shared__ __align__(16) float hp[INH][TWP][4];
    __shared__ float wred[8];

    const int tid = threadIdx.x;

    // ---- XCD-bijective work remap: lid%8 = hw XCD (round-robin) ----
    const int lid = (blockIdx.z * gridDim.y + blockIdx.y) * gridDim.x + blockIdx.x;
    const int wi  = (lid & 7) * (NBLK / 8) + (lid >> 3);
    const int bx  = wi & (NXT - 1);
    const int by  = (wi >> 4) & (NYT - 1);
    const int bz  = wi >> 7;

    const int gx0 = bx * TW;
    const int gy0 = by * TH - 5;
    const size_t plane = (size_t)bz * (size_t)(HH * WW);

    const bool lblk = (bx == 0);
    const bool rblk = (bx == NXT - 1);

    // ---- Phase B: horizontal Gaussian on (a,b,a^2,b^2) from global ----
    // 592 tasks: 74 rows x 8 col-groups, each computes 4 output cols.
    for (int i = tid; i < INH * 8; i += NTHREADS) {
        int r = i >> 3;
        int g = i & 7;
        int c0 = g << 2;
        int gr = gy0 + r;

        if ((unsigned)gr >= (unsigned)HH) {
            float4 z = make_float4(0.f, 0.f, 0.f, 0.f);
            #pragma unroll
            for (int o = 0; o < 4; o++) {
                int phys = (g ^ (o << 1)) + (o << 3);   // phi(c0+o)
                *(float4*)&hp[r][phys][0] = z;
            }
            continue;
        }

        const float* prow = pred + plane + (size_t)gr * WW;
        const float* trow = targ + plane + (size_t)gr * WW;

        v2f ab[14];
        if (lblk && g < 2) {
            // window = cols 0..15; valid iff col >= 0
            float P[16], T[16];
            load16a4(prow, P);
            load16a4(trow, T);
            if (g == 0) {          // col = j-5, valid j>=5
                #pragma unroll
                for (int j = 0; j < 14; j++) {
                    float pv = (j >= 5) ? P[j - 5] : 0.f;
                    float tv = (j >= 5) ? T[j - 5] : 0.f;
                    ab[j] = (v2f){pv + tv, pv - tv};
                }
            } else {               // g==1: col = j-1, valid j>=1
                #pragma unroll
                for (int j = 0; j < 14; j++) {
                    float pv = (j >= 1) ? P[j - 1] : 0.f;
                    float tv = (j >= 1) ? T[j - 1] : 0.f;
                    ab[j] = (v2f){pv + tv, pv - tv};
                }
            }
        } else if (rblk && g > 5) {
            // window = cols 496..511; valid iff col <= 511
            float P[16], T[16];
            load16a4(prow + (WW - 16), P);
            load16a4(trow + (WW - 16), T);
            if (g == 6) {          // col = 499+j, idx j+3, valid j<=12
                #pragma unroll
                for (int j = 0; j < 14; j++) {
                    float pv = (j <= 12) ? P[j + 3] : 0.f;
                    float tv = (j <= 12) ? T[j + 3] : 0.f;
                    ab[j] = (v2f){pv + tv, pv - tv};
                }
            } else {               // g==7: col = 503+j, idx j+7, valid j<=8
                #pragma unroll
                for (int j = 0; j < 14; j++) {
                    float pv = (j <= 8) ? P[j + 7] : 0.f;
                    float tv = (j <= 8) ? T[j + 7] : 0.f;
                    ab[j] = (v2f){pv + tv, pv - tv};
                }
            }
        } else {
            // interior: window = cols gx0+c0-6 .. +9 (base = 2 mod 4 dwords)
            float P[16], T[16];
            load16a2(prow + gx0 + c0 - 6, P);
            load16a2(trow + gx0 + c0 - 6, T);
            #pragma unroll
            for (int j = 0; j < 14; j++) {
                float pv = P[j + 1], tv = T[j + 1];
                ab[j] = (v2f){pv + tv, pv - tv};
            }
        }

        // j-outer conv: v2 hoisted once per input; 2 pk_fma per valid (j,o).
        v2f s1[4], s2[4];
        #pragma unroll
        for (int o = 0; o < 4; o++) { s1[o] = (v2f)(0.f); s2[o] = (v2f)(0.f); }
        #pragma unroll
        for (int j = 0; j < 14; j++) {
            v2f v  = ab[j];
            v2f v2 = v * v;                 // v_pk_mul_f32
            #pragma unroll
            for (int o = 0; o < 4; o++) {
                int k = j - o;
                if (k >= 0 && k < 11) {
                    float wk = gw.w[k];
                    s1[o] += wk * v;        // v_pk_fma_f32
                    s2[o] += wk * v2;       // v_pk_fma_f32
                }
            }
        }
        #pragma unroll
        for (int o = 0; o < 4; o++) {
            int phys = (g ^ (o << 1)) + (o << 3);   // phi(c0+o)
            *(float4*)&hp[r][phys][0] =
                make_float4(s1[o].x, s1[o].y, s2[o].x, s2[o].y);
        }
    }
    __syncthreads();

    // ---- Phase C: vertical Gaussian, 4 rows x 1 col per thread + SSIM ----
    // 512 threads x 4 outputs = 2048 = 32x64 tile. One b128 read per pixel;
    // packed accumulation of (A,B) and (EA,EB).
    float local = 0.f;
    {
        const int c0 = tid & 31;            // logical col 0..31
        const int r0 = (tid >> 5) << 2;     // 0..60
        const int pc = ((c0 >> 2) ^ ((c0 & 3) << 1)) + ((c0 & 3) << 3);  // phi(c0)
        const float* hbase = &hp[r0][pc][0];

        v2f accm[4], acce[4];
        #pragma unroll
        for (int rr = 0; rr < 4; rr++) { accm[rr] = (v2f)(0.f); acce[rr] = (v2f)(0.f); }

        #pragma unroll
        for (int jj = 0; jj < 14; jj++) {
            float4 v = *(const float4*)(hbase + (size_t)jj * (TWP * 4));
            v2f vm = (v2f){v.x, v.y};
            v2f ve = (v2f){v.z, v.w};
            #pragma unroll
            for (int rr = 0; rr < 4; rr++) {
                int k = jj - rr;
                if (k >= 0 && k < 11) {
                    float wk = gw.w[k];
                    accm[rr] += wk * vm;   // v_pk_fma_f32
                    acce[rr] += wk * ve;   // v_pk_fma_f32
                }
            }
        }

        #pragma unroll
        for (int rr = 0; rr < 4; rr++) {
            float A  = accm[rr].x, Bv = accm[rr].y;
            float EA = acce[rr].x, EB = acce[rr].y;
            float A2 = A * A, B2 = Bv * Bv;
            float S  = 0.5f  * (A2 + B2);      // mu1^2 + mu2^2
            float P  = 0.25f * (A2 - B2);      // mu1 * mu2
            float Ep = 0.5f  * (EA + EB);      // e11 + e22
            float Ec = 0.25f * (EA - EB);      // e12
            float num = (2.f * P + C1F) * (2.f * (Ec - P) + C2F);
            float den = (S + C1F) * ((Ep - S) + C2F);
            local += num * __builtin_amdgcn_rcpf(den);
        }
    }

    // ---- block reduction (8 waves) ----
    #pragma unroll
    for (int off = 32; off > 0; off >>= 1)
        local += __shfl_down(local, off, 64);
    int lane = tid & 63, wid = tid >> 6;
    if (lane == 0) wred[wid] = local;
    __syncthreads();
    if (tid == 0) {
        float s = 0.f;
        #pragma unroll
        for (int w2 = 0; w2 < 8; w2++) s += wred[w2];
        partial[lid] = s;
    }
}

// Compile-time N=6144: 6 independent unrolled float4 loads per thread.
__global__ __launch_bounds__(256) void ssim_finalize_kernel(
    const float* __restrict__ partial, float inv_count,
    float* __restrict__ out)
{
    __shared__ float sm[4];
    float s = 0.f;
    #pragma unroll
    for (int i = 0; i < NBLK / 4 / 256; i++) {
        float4 v = *(const float4*)&partial[(threadIdx.x + i * 256) * 4];
        s += (v.x + v.y) + (v.z + v.w);
    }
    #pragma unroll
    for (int off = 32; off > 0; off >>= 1)
        s += __shfl_down(s, off, 64);
    int lane = threadIdx.x & 63, wid = threadIdx.x >> 6;
    if (lane == 0) sm[wid] = s;
    __syncthreads();
    if (threadIdx.x == 0)
        out[0] = 1.0f - (sm[0] + sm[1] + sm[2] + sm[3]) * inv_count;
}

extern "C" void kernel_launch(void* const* d_in, const int* in_sizes, int n_in,
                              void* d_out, int out_size, void* d_ws, size_t ws_size,
                              hipStream_t stream)
{
    const float* pred = (const float*)d_in[0];
    const float* targ = (const float*)d_in[1];
    float* out = (float*)d_out;
    float* partial = (float*)d_ws;

    const int total = in_sizes[0];                 // 16*3*512*512 = 12582912

    GaussW gw;
    double g[11], s = 0.0;
    for (int i = 0; i < 11; i++) {
        double d = (double)(i - 5);
        g[i] = exp(-d * d / 4.5);
        s += g[i];
    }
    for (int i = 0; i < 11; i++) gw.w[i] = (float)(g[i] / s);

    dim3 grid(NXT, NYT, NPL);                      // 16 x 8 x 48 = 6144 blocks
    ssim_tile_kernel<<<grid, NTHREADS, 0, stream>>>(pred, targ, partial, gw);

    const float inv_count = 1.0f / (float)total;
    ssim_finalize_kernel<<<1, 256, 0, stream>>>(partial, inv_count, out);
}